// Round 9
// baseline (305.273 us; speedup 1.0000x reference)
//
#include <hip/hip_runtime.h>

#define NODES 4096

typedef float f32x4 __attribute__((ext_vector_type(4)));
typedef float f32x8 __attribute__((ext_vector_type(8)));
typedef __bf16 bf16x8 __attribute__((ext_vector_type(8)));

__device__ __forceinline__ unsigned short f2bf(float x) {
    unsigned u = __builtin_bit_cast(unsigned, x);
    return (unsigned short)((u + 0x7fffu + ((u >> 16) & 1u)) >> 16);
}

// ---- stage A: h = tanh(x@Wm + bm), stored transposed bf16 [64][4096] -------
__global__ __launch_bounds__(256) void prep_h(
    const float* __restrict__ f0, const float* __restrict__ f1,
    const float* __restrict__ Wm0, const float* __restrict__ bm0,
    const float* __restrict__ Wm1, const float* __restrict__ bm1,
    unsigned short* __restrict__ hT0, unsigned short* __restrict__ hT1)
{
    const int d = threadIdx.x & 63;
    int n = blockIdx.x * 4 + (threadIdx.x >> 6);
    n = __builtin_amdgcn_readfirstlane(n);
    const float* r0 = f0 + (size_t)n * 256;
    float a0 = bm0[d];
#pragma unroll 8
    for (int k = 0; k < 256; ++k) a0 = fmaf(r0[k], Wm0[k * 64 + d], a0);
    hT0[(size_t)d * NODES + n] = f2bf(tanhf(a0));
    const float* r1 = f1 + (size_t)n * 128;
    float a1 = bm1[d];
#pragma unroll 8
    for (int k = 0; k < 128; ++k) a1 = fmaf(r1[k], Wm1[k * 64 + d], a1);
    hT1[(size_t)d * NODES + n] = f2bf(tanhf(a1));
}

// ---- adjacency GEMM: r6 asm streaming schedule, 64 rows/wave (B:A = 1:2) ---
// Each wave: independent 64-row x 64-col x k-chunk unit. 4 row-tiles share one
// B-tile -> B bytes through L1 halved vs A (was 2x A in r1/r6 -> the L1-byte
// cap starved A at 2.5 TB/s). Per 32-k tile: 12 asm loads (8 A f32 + 4 B bf16)
// issued as one group, depth-2 sets, s_waitcnt vmcnt(12) (never 0 mid-loop),
// sched_barrier after each wait (rule #18). No barriers, no LDS in the loop.
// Raw sums atomicAdd'ed into zeroed output (k-split adders); tanh deferred.
// Fragment map (r1/r6-verified): lane=(fr,fg): A[row0+rt*16+fr][k+fg*8..+8],
// B=hT[ct*16+fr][same k]; acc[rt][ct][j] -> C[row0+rt*16+fg*4+j][ct*16+fr].

#define GL16(dst, addr, off) \
    asm volatile("global_load_dwordx4 %0, %1, off offset:" off \
                 : "=v"(dst) : "v"(addr))

#define WAITN(n) \
    asm volatile("s_waitcnt vmcnt(" #n ")" ::: "memory"); \
    __builtin_amdgcn_sched_barrier(0)

#define ISSUE_EVEN(S)                                      \
    GL16(S##_a00, aA0, "0");  GL16(S##_a01, aA0, "16");    \
    GL16(S##_a10, aA1, "0");  GL16(S##_a11, aA1, "16");    \
    GL16(S##_a20, aA2, "0");  GL16(S##_a21, aA2, "16");    \
    GL16(S##_a30, aA3, "0");  GL16(S##_a31, aA3, "16");    \
    GL16(S##_b0, bA0, "0");   GL16(S##_b1, bA1, "0");      \
    GL16(S##_b2, bA2, "0");   GL16(S##_b3, bA3, "0")

#define ISSUE_ODD(S)                                       \
    GL16(S##_a00, aA0, "128"); GL16(S##_a01, aA0, "144");  \
    GL16(S##_a10, aA1, "128"); GL16(S##_a11, aA1, "144");  \
    GL16(S##_a20, aA2, "128"); GL16(S##_a21, aA2, "144");  \
    GL16(S##_a30, aA3, "128"); GL16(S##_a31, aA3, "144");  \
    GL16(S##_b0, bA0, "64");   GL16(S##_b1, bA1, "64");    \
    GL16(S##_b2, bA2, "64");   GL16(S##_b3, bA3, "64")

#define CONS_RT(S, A0f, A1f, c0, c1, c2, c3) {                                 \
    f32x8 av = __builtin_shufflevector(S##_##A0f, S##_##A1f, 0,1,2,3,4,5,6,7); \
    bf16x8 af = __builtin_convertvector(av, bf16x8);                           \
    c0 = __builtin_amdgcn_mfma_f32_16x16x32_bf16(af, __builtin_bit_cast(bf16x8, S##_b0), c0, 0, 0, 0); \
    c1 = __builtin_amdgcn_mfma_f32_16x16x32_bf16(af, __builtin_bit_cast(bf16x8, S##_b1), c1, 0, 0, 0); \
    c2 = __builtin_amdgcn_mfma_f32_16x16x32_bf16(af, __builtin_bit_cast(bf16x8, S##_b2), c2, 0, 0, 0); \
    c3 = __builtin_amdgcn_mfma_f32_16x16x32_bf16(af, __builtin_bit_cast(bf16x8, S##_b3), c3, 0, 0, 0); }

#define CONSUME(S)                                         \
    CONS_RT(S, a00, a01, acc00, acc01, acc02, acc03);      \
    CONS_RT(S, a10, a11, acc10, acc11, acc12, acc13);      \
    CONS_RT(S, a20, a21, acc20, acc21, acc22, acc23);      \
    CONS_RT(S, a30, a31, acc30, acc31, acc32, acc33)

__global__ __launch_bounds__(256, 2) void adj_gemm(
    const float* __restrict__ A0, const float* __restrict__ A1,
    const float* __restrict__ A2, const float* __restrict__ A3,
    const float* __restrict__ A4,
    const unsigned short* __restrict__ hTa, const unsigned short* __restrict__ hTb,
    int split, float* __restrict__ outBase, int kslotBits, int nt)
{
    const int job = blockIdx.y;
    const float* adj = job == 0 ? A0 : job == 1 ? A1 : job == 2 ? A2 : job == 3 ? A3 : A4;
    const unsigned short* hT = (job < split) ? hTa : hTb;

    const int lane = threadIdx.x & 63;
    const int wid = threadIdx.x >> 6;
    const int fr = lane & 15, fg = lane >> 4;

    const int unit = blockIdx.x * 4 + wid;
    const int group = unit >> kslotBits;
    const int kslot = unit & ((1 << kslotBits) - 1);
    const int row0 = group * 64;
    const int kbeg = kslot * (nt * 32);

    const char* aA0 = (const char*)adj + ((size_t)(row0 +  0 + fr) * NODES + kbeg + fg * 8) * 4;
    const char* aA1 = (const char*)adj + ((size_t)(row0 + 16 + fr) * NODES + kbeg + fg * 8) * 4;
    const char* aA2 = (const char*)adj + ((size_t)(row0 + 32 + fr) * NODES + kbeg + fg * 8) * 4;
    const char* aA3 = (const char*)adj + ((size_t)(row0 + 48 + fr) * NODES + kbeg + fg * 8) * 4;
    const char* bA0 = (const char*)hT + ((size_t)( 0 + fr) * NODES + kbeg + fg * 8) * 2;
    const char* bA1 = (const char*)hT + ((size_t)(16 + fr) * NODES + kbeg + fg * 8) * 2;
    const char* bA2 = (const char*)hT + ((size_t)(32 + fr) * NODES + kbeg + fg * 8) * 2;
    const char* bA3 = (const char*)hT + ((size_t)(48 + fr) * NODES + kbeg + fg * 8) * 2;

    f32x4 acc00 = {0,0,0,0}, acc01 = {0,0,0,0}, acc02 = {0,0,0,0}, acc03 = {0,0,0,0};
    f32x4 acc10 = {0,0,0,0}, acc11 = {0,0,0,0}, acc12 = {0,0,0,0}, acc13 = {0,0,0,0};
    f32x4 acc20 = {0,0,0,0}, acc21 = {0,0,0,0}, acc22 = {0,0,0,0}, acc23 = {0,0,0,0};
    f32x4 acc30 = {0,0,0,0}, acc31 = {0,0,0,0}, acc32 = {0,0,0,0}, acc33 = {0,0,0,0};

    f32x4 S0_a00, S0_a01, S0_a10, S0_a11, S0_a20, S0_a21, S0_a30, S0_a31;
    f32x4 S0_b0, S0_b1, S0_b2, S0_b3;
    f32x4 S1_a00, S1_a01, S1_a10, S1_a11, S1_a20, S1_a21, S1_a30, S1_a31;
    f32x4 S1_b0, S1_b1, S1_b2, S1_b3;

    // prologue: tiles 0 (->S0) and 1 (->S1); bases then point at tile 2
    ISSUE_EVEN(S0);
    ISSUE_ODD(S1);
    aA0 += 256; aA1 += 256; aA2 += 256; aA3 += 256;
    bA0 += 128; bA1 += 128; bA2 += 128; bA3 += 128;

    for (int t = 0; t + 2 < nt; t += 2) {
        WAITN(12);           // tile t complete (t+1's 12 loads stay in flight)
        CONSUME(S0);
        ISSUE_EVEN(S0);      // tile t+2
        WAITN(12);           // tile t+1 complete
        CONSUME(S1);
        ISSUE_ODD(S1);       // tile t+3
        aA0 += 256; aA1 += 256; aA2 += 256; aA3 += 256;
        bA0 += 128; bA1 += 128; bA2 += 128; bA3 += 128;
    }
    WAITN(12);
    CONSUME(S0);             // tile nt-2
    WAITN(0);
    CONSUME(S1);             // tile nt-1

    // acc[rt][ct][j] -> C[row0+rt*16+fg*4+j][ct*16+fr], atomic k-split combine
    float* C = outBase + (size_t)job * (NODES * 64);
#define WR_RT(rt, c0, c1, c2, c3) {                                          \
    float* Cw = C + (size_t)(row0 + (rt) * 16 + fg * 4) * 64 + fr;           \
    _Pragma("unroll")                                                        \
    for (int j = 0; j < 4; ++j) {                                            \
        atomicAdd(&Cw[j * 64 + 0],  c0[j]);                                  \
        atomicAdd(&Cw[j * 64 + 16], c1[j]);                                  \
        atomicAdd(&Cw[j * 64 + 32], c2[j]);                                  \
        atomicAdd(&Cw[j * 64 + 48], c3[j]);                                  \
    } }
    WR_RT(0, acc00, acc01, acc02, acc03);
    WR_RT(1, acc10, acc11, acc12, acc13);
    WR_RT(2, acc20, acc21, acc22, acc23);
    WR_RT(3, acc30, acc31, acc32, acc33);
#undef WR_RT
}

// ---- stage C: semantic-attention logits + schema softmax -> iccT bf16 [64][4096]
// agg holds RAW sums; hr = tanh(raw) applied here.
__global__ __launch_bounds__(128) void stage_c(
    const float* __restrict__ agg, const float* __restrict__ Wa,
    const float* __restrict__ ba, const float* __restrict__ qa,
    const float* __restrict__ wsv, float* __restrict__ sacc,
    unsigned short* __restrict__ iccT)
{
    const int n = blockIdx.x;
    const int p = threadIdx.x;          // 0..127 = PROJ lanes
    __shared__ float rs[3][2];
    __shared__ float ru[2][2];
    __shared__ float th[3][64];

    const float* h0p = agg + (size_t)n * 64;
    const float* h1p = agg + ((size_t)NODES + n) * 64;
    const float* h2p = agg + ((size_t)2 * NODES + n) * 64;
    if (p < 64) {
        th[0][p] = tanhf(h0p[p]);
        th[1][p] = tanhf(h1p[p]);
        th[2][p] = tanhf(h2p[p]);
    }
    __syncthreads();
    float a0 = ba[p], a1 = a0, a2 = a0;
#pragma unroll 8
    for (int d = 0; d < 64; ++d) {
        float w = Wa[d * 128 + p];
        a0 = fmaf(th[0][d], w, a0);
        a1 = fmaf(th[1][d], w, a1);
        a2 = fmaf(th[2][d], w, a2);
    }
    float qv = qa[p];
    float v0 = tanhf(a0) * qv, v1 = tanhf(a1) * qv, v2 = tanhf(a2) * qv;

    const float* z0 = agg + ((size_t)3 * NODES + n) * 64;
    const float* z1 = agg + ((size_t)4 * NODES + n) * 64;
    float u0 = (p < 64) ? z0[p] * wsv[p] : 0.f;
    float u1 = (p < 64) ? z1[p] * wsv[p] : 0.f;

#pragma unroll
    for (int off = 32; off; off >>= 1) {
        v0 += __shfl_down(v0, off); v1 += __shfl_down(v1, off); v2 += __shfl_down(v2, off);
        u0 += __shfl_down(u0, off); u1 += __shfl_down(u1, off);
    }
    if ((p & 63) == 0) {
        int w = p >> 6;
        rs[0][w] = v0; rs[1][w] = v1; rs[2][w] = v2;
        ru[0][w] = u0; ru[1][w] = u1;
    }
    __syncthreads();
    if (p < 3) atomicAdd(&sacc[p], rs[p][0] + rs[p][1]);

    float U0 = ru[0][0] + ru[0][1];
    float U1 = ru[1][0] + ru[1][1];
    float mx = fmaxf(U0, U1);
    float e0 = expf(U0 - mx), e1 = expf(U1 - mx);
    float inv = 1.f / (e0 + e1);
    if (p < 64) {
        float icc = (e0 * z0[p] + e1 * z1[p]) * inv;
        iccT[(size_t)p * NODES + n] = f2bf(icc);
    }
}

// ---- stage E: relation_agg, item-item attention, AggAttention, projection --
// ym holds raw sums (atomic-accumulated); tanh applied here. agg raw -> tanh.
__global__ __launch_bounds__(256) void finalize(
    const float* __restrict__ agg, const float* __restrict__ ym,
    const float* __restrict__ sacc,
    const float* __restrict__ Wc1, const float* __restrict__ bc1, const float* __restrict__ wc2,
    const float* __restrict__ Wt1, const float* __restrict__ bt1, const float* __restrict__ wt2,
    const float* __restrict__ Wp, const float* __restrict__ bp,
    float* __restrict__ out)
{
    __shared__ float sWc[64 * 128];
    __shared__ float sWp[64 * 16];
    __shared__ float sY0[2][64], sY1[2][64];
    __shared__ float sHs0[2][64], sHs1[2][64], sHv[2][64];
    __shared__ float rA[2][2], rB[2][2];

    const int t = threadIdx.x;
    for (int i = t; i < 64 * 128; i += 256) sWc[i] = Wc1[i];
    for (int i = t; i < 64 * 16; i += 256) sWp[i] = Wp[i];

    float s0 = sacc[0] * (1.f / NODES), s1 = sacc[1] * (1.f / NODES), s2 = sacc[2] * (1.f / NODES);
    float sm = fmaxf(s0, fmaxf(s1, s2));
    float b0 = expf(s0 - sm), b1 = expf(s1 - sm), b2 = expf(s2 - sm);
    float bi = 1.f / (b0 + b1 + b2);
    b0 *= bi; b1 *= bi; b2 *= bi;

    const int sub = t >> 7;       // 2 nodes processed in parallel
    const int p = t & 127;
    const int wiH = p >> 6;
    const float bcv = bc1[p], wcv = wc2[p], btv = bt1[p], wtv = wt2[p];
    __syncthreads();

    for (int it = 0; it < 8; ++it) {
        const int n = blockIdx.x * 16 + it * 2 + sub;
        if (p < 64) {
            const size_t NN64 = (size_t)NODES * 64;
            sY0[sub][p] = tanhf(ym[(size_t)n * 64 + p]);
            sY1[sub][p] = tanhf(ym[NN64 + (size_t)n * 64 + p]);
            sHs0[sub][p] = b0 * tanhf(agg[(size_t)n * 64 + p])
                         + b1 * tanhf(agg[((size_t)NODES + n) * 64 + p])
                         + b2 * tanhf(agg[((size_t)2 * NODES + n) * 64 + p]);
        }
        __syncthreads();
        float ac0 = bcv, ac1 = bcv;
#pragma unroll 8
        for (int d = 0; d < 64; ++d) {
            float w = sWc[d * 128 + p];
            ac0 = fmaf(sY0[sub][d], w, ac0);
            ac1 = fmaf(sY1[sub][d], w, ac1);
        }
        float v0 = tanhf(ac0) * wcv, v1 = tanhf(ac1) * wcv;
#pragma unroll
        for (int off = 32; off; off >>= 1) { v0 += __shfl_down(v0, off); v1 += __shfl_down(v1, off); }
        if ((p & 63) == 0) { rA[sub][wiH] = v0; rB[sub][wiH] = v1; }
        __syncthreads();
        float wm0 = rA[sub][0] + rA[sub][1];
        float wm1 = rB[sub][0] + rB[sub][1];
        float mm = fmaxf(wm0, wm1);
        float g0 = expf(wm0 - mm), g1 = expf(wm1 - mm);
        float gi = 1.f / (g0 + g1);
        g0 *= gi; g1 *= gi;
        if (p < 64) sHs1[sub][p] = g0 * sY0[sub][p] + g1 * sY1[sub][p];
        __syncthreads();

        float at0 = btv, at1 = btv;
#pragma unroll 8
        for (int d = 0; d < 64; ++d) {
            float w = Wt1[d * 128 + p];
            at0 = fmaf(sHs0[sub][d], w, at0);
            at1 = fmaf(sHs1[sub][d], w, at1);
        }
        float q0 = tanhf(at0) * wtv, q1 = tanhf(at1) * wtv;
#pragma unroll
        for (int off = 32; off; off >>= 1) { q0 += __shfl_down(q0, off); q1 += __shfl_down(q1, off); }
        if ((p & 63) == 0) { rA[sub][wiH] = q0; rB[sub][wiH] = q1; }
        __syncthreads();
        float t0 = rA[sub][0] + rA[sub][1];
        float t1 = rB[sub][0] + rB[sub][1];
        float tm = fmaxf(t0, t1);
        float c0 = expf(t0 - tm), c1 = expf(t1 - tm);
        float ci = 1.f / (c0 + c1);
        c0 *= ci; c1 *= ci;
        if (p < 64) {
            float H = c0 * sHs0[sub][p] + c1 * sHs1[sub][p];
            sHv[sub][p] = H;
            out[(size_t)NODES * 16 + (size_t)n * 64 + p] = H;
        }
        __syncthreads();
        if (p < 16) {
            float a = bp[p];
#pragma unroll 8
            for (int d = 0; d < 64; ++d) a = fmaf(sHv[sub][d], sWp[d * 16 + p], a);
            out[(size_t)n * 16 + p] = a;
        }
        __syncthreads();
    }
}

extern "C" void kernel_launch(void* const* d_in, const int* in_sizes, int n_in,
                              void* d_out, int out_size, void* d_ws, size_t ws_size,
                              hipStream_t stream)
{
    const float* f0   = (const float*)d_in[0];
    const float* f1   = (const float*)d_in[1];
    const float* adjS = (const float*)d_in[2];
    const float* adjM = (const float*)d_in[3];
    const float* adjK = (const float*)d_in[4];
    const float* Wm0  = (const float*)d_in[5];
    const float* bm0  = (const float*)d_in[6];
    const float* Wm1  = (const float*)d_in[7];
    const float* bm1  = (const float*)d_in[8];
    const float* Wa   = (const float*)d_in[9];
    const float* ba   = (const float*)d_in[10];
    const float* qa   = (const float*)d_in[11];
    const float* wsv  = (const float*)d_in[12];
    const float* Wc1  = (const float*)d_in[13];
    const float* bc1  = (const float*)d_in[14];
    const float* wc2  = (const float*)d_in[15];
    const float* Wt1  = (const float*)d_in[16];
    const float* bt1  = (const float*)d_in[17];
    const float* wt2  = (const float*)d_in[18];
    const float* Wp   = (const float*)d_in[19];
    const float* bpv  = (const float*)d_in[20];
    float* out = (float*)d_out;

    // workspace layout (bytes) — total ~8.5 MB:
    //   0        hT0   512 KB  (row-major transposed bf16 [64][4096])
    //   524288   hT1   512 KB
    //   1048576  iccT  512 KB
    //   1572864  agg   5 MB   (raw sums hr0..2, zk0..1; atomic-accumulated)
    //   6815744  ym    2 MB   (raw sums, 2 slots; atomic-accumulated)
    //   8912896  sacc  64 B
    char* ws = (char*)d_ws;
    unsigned short* hT0  = (unsigned short*)(ws);
    unsigned short* hT1  = (unsigned short*)(ws + 524288);
    unsigned short* iccT = (unsigned short*)(ws + 1048576);
    float* agg           = (float*)(ws + 1572864);
    float* ym            = (float*)(ws + 6815744);
    float* sacc          = (float*)(ws + 8912896);

    hipMemsetAsync(agg, 0, 7 * 1048576, stream);   // agg + ym contiguous
    hipMemsetAsync(sacc, 0, 64, stream);
    prep_h<<<dim3(1024), dim3(256), 0, stream>>>(f0, f1, Wm0, bm0, Wm1, bm1, hT0, hT1);

    const size_t NNs = (size_t)NODES * NODES;
    // gemm5: 64 row-groups x 8 k-slots x 5 jobs; 4 wave-units/block -> 128 x 5
    adj_gemm<<<dim3(128, 5), dim3(256), 0, stream>>>(
        adjM, adjM + NNs, adjM + 2 * NNs, adjK, adjK + NNs,
        hT0, hT1, 3, agg, 3, 16);
    stage_c<<<dim3(4096), dim3(128), 0, stream>>>(agg, Wa, ba, qa, wsv, sacc, iccT);
    // gemm2: 64 row-groups x 16 k-slots x 2 jobs -> 256 x 2 blocks
    adj_gemm<<<dim3(256, 2), dim3(256), 0, stream>>>(
        adjS, adjS + NNs, adjS, adjS, adjS,
        iccT, iccT, 5, ym, 4, 8);
    finalize<<<dim3(256), dim3(256), 0, stream>>>(
        agg, ym, sacc, Wc1, bc1, wc2, Wt1, bt1, wt2, Wp, bpv, out);
}